// Round 3
// baseline (9843.385 us; speedup 1.0000x reference)
//
#include <hip/hip_runtime.h>
#include <hip/hip_bf16.h>

#define NEG 0.01f
#define BN_EPS 1e-5f

typedef __hip_bfloat16 bf16;
typedef __attribute__((ext_vector_type(8))) short short8;
typedef __attribute__((ext_vector_type(16))) float f32x16;

// ---------------- small kernels ----------------

__global__ void zero_stats_k(float* s) {
    s[blockIdx.x * blockDim.x + threadIdx.x] = 0.f;
}

// stats slot layout: [sum(64), sumsq(64), mean(64), rstd(64)] = 256 floats
__global__ void finalize_k(float* stats, int slotA, int slotB, float inv_n) {
    int slot = (blockIdx.x == 0) ? slotA : slotB;
    float* s = stats + (size_t)slot * 256;
    int c = threadIdx.x;  // 64 threads
    float m = s[c] * inv_n;
    float v = s[64 + c] * inv_n - m * m;
    s[128 + c] = m;
    s[192 + c] = rsqrtf(v + BN_EPS);
}

// y = leaky((x - m) * r), elementwise, channel = i & 63 (in-place safe)
__global__ void bnact_k(const bf16* __restrict__ x, const float* __restrict__ m,
                        const float* __restrict__ r, bf16* __restrict__ y, int n) {
    int i = blockIdx.x * blockDim.x + threadIdx.x;
    if (i >= n) return;
    int c = i & 63;
    float v = ((float)x[i] - m[c]) * r[c];
    y[i] = __float2bfloat16(v > 0.f ? v : NEG * v);
}

// out = bnact(a) + bnact(b)
__global__ void bn2_add(const bf16* __restrict__ a, const float* __restrict__ ma,
                        const float* __restrict__ ra, const bf16* __restrict__ b,
                        const float* __restrict__ mb, const float* __restrict__ rb,
                        bf16* __restrict__ out, int n_elem) {
    int i = blockIdx.x * blockDim.x + threadIdx.x;
    if (i >= n_elem) return;
    int c = i & 63;
    float va = ((float)a[i] - ma[c]) * ra[c];
    va = va > 0.f ? va : NEG * va;
    float vb = ((float)b[i] - mb[c]) * rb[c];
    vb = vb > 0.f ? vb : NEG * vb;
    out[i] = __float2bfloat16(va + vb);
}

__global__ void cvt_bf16_k(const float* __restrict__ x, bf16* __restrict__ y, int n) {
    int i = blockIdx.x * blockDim.x + threadIdx.x;
    if (i < n) y[i] = __float2bfloat16(x[i]);
}

// ---------------- weight pack ----------------
// Packed B-fragment layout per (tap k, K-step s, col-tile c): 64 lanes x 8 bf16,
// elem j of lane l = W[k][s*16 + (l>>5)*8 + j][c*32 + (l&31)]
struct PackEnt { const float* src; bf16* dst; int kt; int ns; };
struct PackArgs { PackEnt e[16]; };

__global__ void pack_w_k(PackArgs pa) {
    PackEnt E = pa.e[blockIdx.y];
    int cin = E.ns * 16;
    int total = E.kt * E.ns * 1024;  // bf16 elems
    for (int i = blockIdx.x * blockDim.x + threadIdx.x; i < total;
         i += gridDim.x * blockDim.x) {
        int j = i & 7, lane = (i >> 3) & 63, c = (i >> 9) & 1;
        int rem = i >> 10;
        int s = rem % E.ns, k = rem / E.ns;
        int krow = s * 16 + ((lane >> 5) << 3) + j;
        int col = c * 32 + (lane & 31);
        E.dst[i] = __float2bfloat16(E.src[((size_t)k * cin + krow) * 64 + col]);
    }
}

// ---------------- MFMA sparse conv ----------------
// One wave per 32-output-row tile; cout=64 as 2 col-tiles of 32.
// v_mfma_f32_32x32x16_bf16: A[m=lane&31][k=(lane>>5)*8+j], B[k][n=lane&31],
// C/D: col=lane&31, row=(reg&3)+8*(reg>>2)+4*(lane>>5).
// Sentinel neighbor idx == n_in -> zero A row; tap skipped if no row active.
template <int NS, int K>  // NS = CIN/16, K = taps
__global__ __launch_bounds__(256) void mconv(
    const bf16* __restrict__ fin, const int* __restrict__ nbr,
    const bf16* __restrict__ Wp, bf16* __restrict__ out,
    float* __restrict__ stat, int n_out, int n_in) {
    const int CIN = NS * 16;
    const int lane = threadIdx.x & 63;
    const int wid = blockIdx.x * (blockDim.x >> 6) + (threadIdx.x >> 6);
    const int nw = gridDim.x * (blockDim.x >> 6);
    const int ntiles = (n_out + 31) >> 5;

    for (int tile = wid; tile < ntiles; tile += nw) {
        const int rbase = tile << 5;
        const int r = rbase + (lane & 31);
        const bool rowok = r < n_out;

        f32x16 acc0, acc1;
        #pragma unroll
        for (int i = 0; i < 16; ++i) { acc0[i] = 0.f; acc1[i] = 0.f; }

        for (int k = 0; k < K; ++k) {
            int idx = rowok ? nbr[(size_t)k * n_out + r] : n_in;
            bool v = idx < n_in;
            if (__ballot(v) == 0ull) continue;
            short8 a[NS];
            const bf16* src = fin + (size_t)idx * CIN + ((lane >> 5) << 3);
            #pragma unroll
            for (int s = 0; s < NS; ++s) {
                if (v) a[s] = *(const short8*)(src + s * 16);
                else { short8 z = {0,0,0,0,0,0,0,0}; a[s] = z; }
            }
            const short8* wp = (const short8*)(Wp + (size_t)k * (NS * 1024)) + lane;
            #pragma unroll
            for (int s = 0; s < NS; ++s) {
                short8 b0 = wp[(s * 2 + 0) * 64];
                short8 b1 = wp[(s * 2 + 1) * 64];
                acc0 = __builtin_amdgcn_mfma_f32_32x32x16_bf16(a[s], b0, acc0, 0, 0, 0);
                acc1 = __builtin_amdgcn_mfma_f32_32x32x16_bf16(a[s], b1, acc1, 0, 0, 0);
            }
        }

        float ssum0 = 0.f, ssq0 = 0.f, ssum1 = 0.f, ssq1 = 0.f;
        const int col = lane & 31;
        #pragma unroll
        for (int i = 0; i < 16; ++i) {
            int row = (i & 3) + 8 * (i >> 2) + 4 * (lane >> 5);
            int gr = rbase + row;
            if (gr < n_out) {
                float v0 = acc0[i], v1 = acc1[i];
                out[(size_t)gr * 64 + col] = __float2bfloat16(v0);
                out[(size_t)gr * 64 + 32 + col] = __float2bfloat16(v1);
                ssum0 += v0; ssq0 += v0 * v0;
                ssum1 += v1; ssq1 += v1 * v1;
            }
        }
        if (stat != nullptr) {
            atomicAdd(&stat[col], ssum0);
            atomicAdd(&stat[64 + col], ssq0);
            atomicAdd(&stat[32 + col], ssum1);
            atomicAdd(&stat[96 + col], ssq1);
        }
    }
}

// ---------------- dense MFMA down-projection ----------------
// out(fp32, m x 64) (+)= x(bf16, m x 64) @ W(64x64, packed)
__global__ __launch_bounds__(256) void down_mfma(
    const bf16* __restrict__ x, const bf16* __restrict__ Wp,
    float* __restrict__ out, int m, int accum) {
    const int lane = threadIdx.x & 63;
    const int wid = blockIdx.x * (blockDim.x >> 6) + (threadIdx.x >> 6);
    const int nw = gridDim.x * (blockDim.x >> 6);
    const int ntiles = (m + 31) >> 5;
    const int col = lane & 31;

    for (int tile = wid; tile < ntiles; tile += nw) {
        const int rbase = tile << 5;
        const int r = rbase + (lane & 31);
        const bool rowok = r < m;

        f32x16 acc0, acc1;
        if (accum) {
            #pragma unroll
            for (int i = 0; i < 16; ++i) {
                int row = (i & 3) + 8 * (i >> 2) + 4 * (lane >> 5);
                int gr = rbase + row;
                acc0[i] = (gr < m) ? out[(size_t)gr * 64 + col] : 0.f;
                acc1[i] = (gr < m) ? out[(size_t)gr * 64 + 32 + col] : 0.f;
            }
        } else {
            #pragma unroll
            for (int i = 0; i < 16; ++i) { acc0[i] = 0.f; acc1[i] = 0.f; }
        }

        short8 a[4];
        const bf16* src = x + (size_t)r * 64 + ((lane >> 5) << 3);
        #pragma unroll
        for (int s = 0; s < 4; ++s) {
            if (rowok) a[s] = *(const short8*)(src + s * 16);
            else { short8 z = {0,0,0,0,0,0,0,0}; a[s] = z; }
        }
        const short8* wp = (const short8*)Wp + lane;
        #pragma unroll
        for (int s = 0; s < 4; ++s) {
            short8 b0 = wp[(s * 2 + 0) * 64];
            short8 b1 = wp[(s * 2 + 1) * 64];
            acc0 = __builtin_amdgcn_mfma_f32_32x32x16_bf16(a[s], b0, acc0, 0, 0, 0);
            acc1 = __builtin_amdgcn_mfma_f32_32x32x16_bf16(a[s], b1, acc1, 0, 0, 0);
        }

        #pragma unroll
        for (int i = 0; i < 16; ++i) {
            int row = (i & 3) + 8 * (i >> 2) + 4 * (lane >> 5);
            int gr = rbase + row;
            if (gr < m) {
                out[(size_t)gr * 64 + col] = acc0[i];
                out[(size_t)gr * 64 + 32 + col] = acc1[i];
            }
        }
    }
}

// ---------------- host ----------------

static inline int conv_grid(int n) { return ((((n + 31) >> 5) + 3) >> 2); }

extern "C" void kernel_launch(void* const* d_in, const int* in_sizes, int n_in_,
                              void* d_out, int out_size, void* d_ws,
                              size_t ws_size, hipStream_t stream) {
    const float* feats  = (const float*)d_in[0];
    const float* Wsrc[16] = {
        (const float*)d_in[1],   // b1_w1   kt9 ns2
        (const float*)d_in[2],   // b1_w12  kt9 ns4
        (const float*)d_in[3],   // b1_w2   kt9 ns2
        (const float*)d_in[4],   // b1_w22  kt9 ns4
        (const float*)d_in[5],   // pool    kt27 ns4
        (const float*)d_in[6], (const float*)d_in[7],
        (const float*)d_in[8], (const float*)d_in[9],     // b2 x4 kt9 ns4
        (const float*)d_in[10], (const float*)d_in[11],
        (const float*)d_in[12], (const float*)d_in[13],   // b3 x4 kt9 ns4
        (const float*)d_in[14],                            // down part1 kt1 ns4
        (const float*)d_in[14] + 64 * 64,                  // down part2
        (const float*)d_in[14] + 128 * 64,                 // down part3
    };
    const int kts[16] = {9,9,9,9, 27, 9,9,9,9, 9,9,9,9, 1,1,1};
    const int nss[16] = {2,4,2,4,  4, 4,4,4,4, 4,4,4,4, 4,4,4};

    const int* nA1  = (const int*)d_in[15];
    const int* nB1  = (const int*)d_in[16];
    const int* pnbr = (const int*)d_in[17];
    const int* nA2  = (const int*)d_in[18];
    const int* nB2  = (const int*)d_in[19];
    const int* nA3  = (const int*)d_in[20];
    const int* nB3  = (const int*)d_in[21];

    const int N = in_sizes[0] / 32;
    const int M = in_sizes[17] / 27;
    const size_t MX = (size_t)(N > M ? N : M);

    // workspace layout (bf16 region first, then fp32 stats)
    bf16* B0 = (bf16*)d_ws;
    bf16* B1 = B0 + MX * 64;
    bf16* B2 = B1 + MX * 64;
    bf16* FB = B2 + MX * 64;          // feats as bf16, N x 32
    bf16* WP = FB + (size_t)N * 32;   // packed weights
    // packed offsets (bf16 elems): entry size = kt * ns * 1024
    bf16* Wp[16];
    {
        size_t off = 0;
        for (int i = 0; i < 16; ++i) {
            Wp[i] = WP + off;
            off += (size_t)kts[i] * nss[i] * 1024;
        }
    }
    size_t wp_total = 0;
    for (int i = 0; i < 16; ++i) wp_total += (size_t)kts[i] * nss[i] * 1024;
    float* ST = (float*)(WP + wp_total + (wp_total & 1));  // 12 slots x 256 f32

    float* out = (float*)d_out;
    auto S = [&](int i) { return ST + (size_t)i * 256; };

    // ---- prep ----
    PackArgs pa;
    for (int i = 0; i < 16; ++i) { pa.e[i] = {Wsrc[i], Wp[i], kts[i], nss[i]}; }
    pack_w_k<<<dim3(64, 16), 256, 0, stream>>>(pa);
    cvt_bf16_k<<<(N * 32 + 255) / 256, 256, 0, stream>>>(feats, FB, N * 32);
    zero_stats_k<<<12, 256, 0, stream>>>(ST);

    const float invN = 1.f / (float)N, invM = 1.f / (float)M;
    const int neN = N * 64, neM = M * 64;
    const int gN = conv_grid(N), gM = conv_grid(M);
    const int eN = (neN + 255) / 256, eM = (neM + 255) / 256;

    // ---- block 1 @ N, C 32->64 ----
    mconv<2, 9><<<gN, 256, 0, stream>>>(FB, nA1, Wp[0], B0, S(0), N, N);
    mconv<2, 9><<<gN, 256, 0, stream>>>(FB, nB1, Wp[2], B1, S(2), N, N);
    finalize_k<<<2, 64, 0, stream>>>(ST, 0, 2, invN);
    bnact_k<<<eN, 256, 0, stream>>>(B0, S(0) + 128, S(0) + 192, B0, neN);
    bnact_k<<<eN, 256, 0, stream>>>(B1, S(2) + 128, S(2) + 192, B1, neN);
    mconv<4, 9><<<gN, 256, 0, stream>>>(B0, nB1, Wp[1], B2, S(1), N, N);
    mconv<4, 9><<<gN, 256, 0, stream>>>(B1, nA1, Wp[3], B0, S(3), N, N);
    finalize_k<<<2, 64, 0, stream>>>(ST, 1, 3, invN);
    bn2_add<<<eN, 256, 0, stream>>>(B2, S(1) + 128, S(1) + 192,
                                    B0, S(3) + 128, S(3) + 192, B1, neN);
    // XP = B1 (N x 64)

    // ---- strided pool, K=27: B1 (N,64) -> B2 (M,64) = X1 ----
    mconv<4, 27><<<gM, 256, 0, stream>>>(B1, pnbr, Wp[4], B2, nullptr, M, N);
    down_mfma<<<gM, 256, 0, stream>>>(B2, Wp[13], out, M, 0);

    // ---- block 2 @ M, dilation 2 (fin = B2) ----
    mconv<4, 9><<<gM, 256, 0, stream>>>(B2, nA2, Wp[5], B0, S(4), M, M);
    mconv<4, 9><<<gM, 256, 0, stream>>>(B2, nB2, Wp[7], B1, S(6), M, M);
    finalize_k<<<2, 64, 0, stream>>>(ST, 4, 6, invM);
    bnact_k<<<eM, 256, 0, stream>>>(B0, S(4) + 128, S(4) + 192, B0, neM);
    bnact_k<<<eM, 256, 0, stream>>>(B1, S(6) + 128, S(6) + 192, B1, neM);
    mconv<4, 9><<<gM, 256, 0, stream>>>(B0, nB2, Wp[6], B2, S(5), M, M);
    mconv<4, 9><<<gM, 256, 0, stream>>>(B1, nA2, Wp[8], B0, S(7), M, M);
    finalize_k<<<2, 64, 0, stream>>>(ST, 5, 7, invM);
    bn2_add<<<eM, 256, 0, stream>>>(B2, S(5) + 128, S(5) + 192,
                                    B0, S(7) + 128, S(7) + 192, B1, neM);
    // X2 = B1
    down_mfma<<<gM, 256, 0, stream>>>(B1, Wp[14], out, M, 1);

    // ---- block 3 @ M, dilation 3 (fin = B1) ----
    mconv<4, 9><<<gM, 256, 0, stream>>>(B1, nA3, Wp[9], B0, S(8), M, M);
    mconv<4, 9><<<gM, 256, 0, stream>>>(B1, nB3, Wp[11], B2, S(10), M, M);
    finalize_k<<<2, 64, 0, stream>>>(ST, 8, 10, invM);
    bnact_k<<<eM, 256, 0, stream>>>(B0, S(8) + 128, S(8) + 192, B0, neM);
    bnact_k<<<eM, 256, 0, stream>>>(B2, S(10) + 128, S(10) + 192, B2, neM);
    mconv<4, 9><<<gM, 256, 0, stream>>>(B0, nB3, Wp[10], B1, S(9), M, M);
    mconv<4, 9><<<gM, 256, 0, stream>>>(B2, nA3, Wp[12], B0, S(11), M, M);
    finalize_k<<<2, 64, 0, stream>>>(ST, 9, 11, invM);
    bn2_add<<<eM, 256, 0, stream>>>(B1, S(9) + 128, S(9) + 192,
                                    B0, S(11) + 128, S(11) + 192, B2, neM);
    // X3 = B2
    down_mfma<<<gM, 256, 0, stream>>>(B2, Wp[15], out, M, 1);
}